// Round 1
// baseline (1166.619 us; speedup 1.0000x reference)
//
#include <hip/hip_runtime.h>
#include <math.h>

#define Bsz 4
#define DM 96
#define DI 192
#define NS 16
#define RK 6
#define KK 4
#define HH 32
#define WW 32
#define LL 1024

__device__ __forceinline__ float silu_f(float x) { return x / (1.f + __expf(-x)); }

// pos_k(l) -> flat spatial index h*32+w of scan position l for direction k
__device__ __forceinline__ int pos_k(int k, int l) {
    int h, w;
    if (k < 2) {               // vertical snake: l = col*32 + i
        int j = l >> 5, i = l & 31;
        h = (j & 1) ? (31 - i) : i;
        w = j;
    } else {                   // horizontal snake: l = row*32 + j
        int i = l >> 5, j = l & 31;
        h = i;
        w = (i & 1) ? (31 - j) : j;
    }
    if (k == 1 || k == 3) { h = 31 - h; w = 31 - w; }
    return h * 32 + w;
}

__global__ void zero_stats_k(float* stats) {
    int t = threadIdx.x;
    if (t < 2 * Bsz) stats[t] = 0.f;
}

// xz = einsum('bchw,oc->bohw'); split into xx (raw) and z (silu)
__global__ void in_proj_k(const float* __restrict__ x, const float* __restrict__ w,
                          float* __restrict__ xx, float* __restrict__ zs) {
    int idx = blockIdx.x * 256 + threadIdx.x;       // [b][o][l], l fastest
    int l = idx & (LL - 1);
    int o = (idx >> 10) % (2 * DI);
    int b = idx / (LL * 2 * DI);
    const float* xb = x + (size_t)b * DM * LL + l;
    const float* wr = w + o * DM;
    float acc = 0.f;
#pragma unroll 8
    for (int c = 0; c < DM; c++) acc = fmaf(xb[(size_t)c * LL], wr[c], acc);
    if (o < DI) xx[((size_t)b * DI + o) * LL + l] = acc;
    else        zs[((size_t)b * DI + (o - DI)) * LL + l] = silu_f(acc);
}

// depthwise 3x3 SAME conv + bias + silu
__global__ void conv_k(const float* __restrict__ xx, const float* __restrict__ cw,
                       const float* __restrict__ cb, float* __restrict__ xc) {
    int idx = blockIdx.x * 256 + threadIdx.x;       // [b][d][hw]
    int hw = idx & (LL - 1);
    int d = (idx >> 10) % DI;
    int h = hw >> 5, w = hw & 31;
    int b = idx / (LL * DI);
    const float* xp = xx + ((size_t)b * DI + d) * LL;
    const float* wp = cw + d * 9;
    float acc = cb[d];
#pragma unroll
    for (int kh = 0; kh < 3; kh++) {
        int hh = h + kh - 1;
        if (hh < 0 || hh >= HH) continue;
#pragma unroll
        for (int kw = 0; kw < 3; kw++) {
            int ww2 = w + kw - 1;
            if (ww2 < 0 || ww2 >= WW) continue;
            acc = fmaf(xp[hh * WW + ww2], wp[kh * 3 + kw], acc);
        }
    }
    xc[idx] = silu_f(acc);
}

// xs_t[b][k][l][d] = xc[b][d][pos_k(l)]
__global__ void xs_k(const float* __restrict__ xc, float* __restrict__ xs) {
    int idx = blockIdx.x * 256 + threadIdx.x;
    int d = idx % DI;
    int rest = idx / DI;
    int l = rest & (LL - 1);
    int k = (rest >> 10) & 3;
    int b = rest >> 12;
    int pos = pos_k(k, l);
    xs[idx] = xc[((size_t)b * DI + d) * LL + pos];
}

// x_dbl[b][k][l][c(38)] = sum_d xs[b][k][l][d] * x_proj_w[k][c][d]
__global__ void xdbl_k(const float* __restrict__ xs, const float* __restrict__ xpw,
                       float* __restrict__ xdbl) {
    int idx = blockIdx.x * 256 + threadIdx.x;       // c fastest
    int c = idx % 38;
    int rest = idx / 38;
    int l = rest & (LL - 1);
    int bk = rest >> 10;
    int k = bk & 3;
    const float* xsv = xs + ((size_t)bk * LL + l) * DI;
    const float* wr = xpw + ((size_t)k * 38 + c) * DI;
    float acc = 0.f;
#pragma unroll 8
    for (int d = 0; d < DI; d++) acc = fmaf(xsv[d], wr[d], acc);
    xdbl[idx] = acc;
}

// sequential selective scan: one block per (b,k), thread = d
__global__ void scan_k(const float* __restrict__ xs, const float* __restrict__ xdbl,
                       const float* __restrict__ dtw_g, const float* __restrict__ dtb_g,
                       const float* __restrict__ Alog, const float* __restrict__ Ds,
                       float* __restrict__ ys) {
    int bk = blockIdx.x;            // 0..15
    int k = bk & 3;
    int d = threadIdx.x;            // 0..191
    int kd = k * DI + d;

    float A[NS];
#pragma unroll
    for (int n = 0; n < NS; n++) A[n] = -__expf(Alog[(size_t)kd * NS + n]);
    float dtw[RK];
#pragma unroll
    for (int r = 0; r < RK; r++) dtw[r] = dtw_g[(size_t)kd * RK + r];
    float dtb = dtb_g[kd];
    float Dp = Ds[kd];

    float h[NS];
#pragma unroll
    for (int n = 0; n < NS; n++) h[n] = 0.f;

    const float* xdbase = xdbl + (size_t)bk * LL * 38;
    const float* xsbase = xs + (size_t)bk * LL * DI;
    float* ybase = ys + (size_t)bk * LL * DI;

    for (int l = 0; l < LL; l++) {
        const float* xd = xdbase + l * 38;
        float dt = dtb;
#pragma unroll
        for (int r = 0; r < RK; r++) dt = fmaf(xd[r], dtw[r], dt);
        dt = (dt > 20.f) ? dt : log1pf(__expf(dt));   // softplus
        float u = xsbase[(size_t)l * DI + d];
        float du = dt * u;
        float y = 0.f;
#pragma unroll
        for (int n = 0; n < NS; n++) {
            float a = __expf(dt * A[n]);
            h[n] = fmaf(a, h[n], du * xd[6 + n]);
            y = fmaf(h[n], xd[22 + n], y);
        }
        ybase[(size_t)l * DI + d] = fmaf(Dp, u, y);
    }
}

// cross_merge gather + per-batch sum/sumsq reduction
__global__ void merge_k(const float* __restrict__ ys, float* __restrict__ ym,
                        float* __restrict__ stats) {
    int b = blockIdx.y;
    int f = blockIdx.x * 256 + threadIdx.x;         // c*1024 + hw
    int c = f >> 10;
    int hw = f & 1023;
    int h = hw >> 5, w = hw & 31;

    int l0 = w * 32 + ((w & 1) ? 31 - h : h);
    int hh = 31 - h, ww = 31 - w;
    int l1 = ww * 32 + ((ww & 1) ? 31 - hh : hh);
    int l2 = h * 32 + ((h & 1) ? 31 - w : w);
    int l3 = hh * 32 + ((hh & 1) ? 31 - ww : ww);

    const float* yb = ys + (size_t)b * KK * LL * DI;
    float v = yb[((size_t)0 * LL + l0) * DI + c]
            + yb[((size_t)1 * LL + l1) * DI + c]
            + yb[((size_t)2 * LL + l2) * DI + c]
            + yb[((size_t)3 * LL + l3) * DI + c];
    ym[((size_t)b * DI + c) * LL + hw] = v;

    float s1 = v, s2 = v * v;
#pragma unroll
    for (int off = 32; off > 0; off >>= 1) {
        s1 += __shfl_down(s1, off);
        s2 += __shfl_down(s2, off);
    }
    __shared__ float sh1[4], sh2[4];
    int lane = threadIdx.x & 63, wid = threadIdx.x >> 6;
    if (lane == 0) { sh1[wid] = s1; sh2[wid] = s2; }
    __syncthreads();
    if (threadIdx.x == 0) {
        atomicAdd(&stats[b * 2],     sh1[0] + sh1[1] + sh1[2] + sh1[3]);
        atomicAdd(&stats[b * 2 + 1], sh2[0] + sh2[1] + sh2[2] + sh2[3]);
    }
}

// normalize + gamma/beta + multiply silu(z)
__global__ void yz_k(const float* __restrict__ ym, const float* __restrict__ zs,
                     const float* __restrict__ g, const float* __restrict__ be,
                     const float* __restrict__ stats, float* __restrict__ yz) {
    int idx = blockIdx.x * 256 + threadIdx.x;       // [b][c][hw]
    int c = (idx >> 10) % DI;
    int b = idx / (LL * DI);
    const float Ninv = 1.f / (float)(DI * LL);
    float mu = stats[b * 2] * Ninv;
    float var = stats[b * 2 + 1] * Ninv - mu * mu;
    float rstd = rsqrtf(var + 1e-6f);
    float v = (ym[idx] - mu) * rstd * g[c] + be[c];
    yz[idx] = v * zs[idx];
}

// out = einsum('bchw,oc->bohw')
__global__ void out_k(const float* __restrict__ yz, const float* __restrict__ wo,
                      float* __restrict__ out) {
    int idx = blockIdx.x * 256 + threadIdx.x;       // [b][o][hw]
    int hw = idx & 1023;
    int o = (idx >> 10) % DM;
    int b = idx / (LL * DM);
    const float* yb = yz + (size_t)b * DI * LL + hw;
    const float* wr = wo + o * DI;
    float acc = 0.f;
#pragma unroll 8
    for (int c = 0; c < DI; c++) acc = fmaf(yb[(size_t)c * LL], wr[c], acc);
    out[idx] = acc;
}

extern "C" void kernel_launch(void* const* d_in, const int* in_sizes, int n_in,
                              void* d_out, int out_size, void* d_ws, size_t ws_size,
                              hipStream_t stream) {
    const float* x    = (const float*)d_in[0];
    const float* ipw  = (const float*)d_in[1];
    const float* cw   = (const float*)d_in[2];
    const float* cb   = (const float*)d_in[3];
    const float* xpw  = (const float*)d_in[4];
    const float* dtw  = (const float*)d_in[5];
    const float* dtb  = (const float*)d_in[6];
    const float* Alog = (const float*)d_in[7];
    const float* Ds   = (const float*)d_in[8];
    const float* gng  = (const float*)d_in[9];
    const float* gnb  = (const float*)d_in[10];
    const float* opw  = (const float*)d_in[11];
    float* out = (float*)d_out;

    float* ws = (float*)d_ws;
    // arena (floats)
    const size_t o_xx   = 0;                        // 786432  (reused as ym)
    const size_t o_zs   = o_xx + (size_t)Bsz * DI * LL;        // 786432
    const size_t o_xc   = o_zs + (size_t)Bsz * DI * LL;        // 786432  (reused as yz)
    const size_t o_xs   = o_xc + (size_t)Bsz * DI * LL;        // 3145728
    const size_t o_xdbl = o_xs + (size_t)Bsz * KK * LL * DI;   // 622592
    const size_t o_ys   = o_xdbl + (size_t)Bsz * KK * LL * 38; // 3145728
    const size_t o_st   = o_ys + (size_t)Bsz * KK * LL * DI;   // 8

    float* xx    = ws + o_xx;
    float* zs    = ws + o_zs;
    float* xc    = ws + o_xc;
    float* xs    = ws + o_xs;
    float* xdbl  = ws + o_xdbl;
    float* ys    = ws + o_ys;
    float* stats = ws + o_st;
    float* ym = xx;   // xx dead after conv
    float* yz = xc;   // xc dead after xs gather

    hipLaunchKernelGGL(zero_stats_k, dim3(1), dim3(64), 0, stream, stats);
    hipLaunchKernelGGL(in_proj_k, dim3(6144), dim3(256), 0, stream, x, ipw, xx, zs);
    hipLaunchKernelGGL(conv_k, dim3(3072), dim3(256), 0, stream, xx, cw, cb, xc);
    hipLaunchKernelGGL(xs_k, dim3(49152), dim3(256), 0, stream, xc, xs);
    hipLaunchKernelGGL(xdbl_k, dim3(2432), dim3(256), 0, stream, xs, xpw, xdbl);
    hipLaunchKernelGGL(scan_k, dim3(16), dim3(192), 0, stream,
                       xs, xdbl, dtw, dtb, Alog, Ds, ys);
    hipLaunchKernelGGL(merge_k, dim3(768, 4), dim3(256), 0, stream, ys, ym, stats);
    hipLaunchKernelGGL(yz_k, dim3(3072), dim3(256), 0, stream, ym, zs, gng, gnb, stats, yz);
    hipLaunchKernelGGL(out_k, dim3(1536), dim3(256), 0, stream, yz, opw, out);
}

// Round 2
// 422.378 us; speedup vs baseline: 2.7620x; 2.7620x over previous
//
#include <hip/hip_runtime.h>
#include <math.h>

#define Bsz 4
#define DM 96
#define DI 192
#define NS 16
#define RK 6
#define KK 4
#define HH 32
#define WW 32
#define LL 1024
#define NC 32          // chunks along L
#define CS 32          // chunk size (NC*CS == LL)

__device__ __forceinline__ float silu_f(float x) { return x / (1.f + __expf(-x)); }

// pos_k(l) -> flat spatial index h*32+w of scan position l for direction k
__device__ __forceinline__ int pos_k(int k, int l) {
    int h, w;
    if (k < 2) {               // vertical snake: l = col*32 + i
        int j = l >> 5, i = l & 31;
        h = (j & 1) ? (31 - i) : i;
        w = j;
    } else {                   // horizontal snake: l = row*32 + j
        int i = l >> 5, j = l & 31;
        h = i;
        w = (i & 1) ? (31 - j) : j;
    }
    if (k == 1 || k == 3) { h = 31 - h; w = 31 - w; }
    return h * 32 + w;
}

__global__ void zero_stats_k(float* stats) {
    int t = threadIdx.x;
    if (t < 2 * Bsz) stats[t] = 0.f;
}

// xz = einsum('bchw,oc->bohw'); split into xx (raw) and z (silu)
__global__ void in_proj_k(const float* __restrict__ x, const float* __restrict__ w,
                          float* __restrict__ xx, float* __restrict__ zs) {
    int idx = blockIdx.x * 256 + threadIdx.x;       // [b][o][l], l fastest
    int l = idx & (LL - 1);
    int o = (idx >> 10) % (2 * DI);
    int b = idx / (LL * 2 * DI);
    const float* xb = x + (size_t)b * DM * LL + l;
    const float* wr = w + o * DM;
    float acc = 0.f;
#pragma unroll 8
    for (int c = 0; c < DM; c++) acc = fmaf(xb[(size_t)c * LL], wr[c], acc);
    if (o < DI) xx[((size_t)b * DI + o) * LL + l] = acc;
    else        zs[((size_t)b * DI + (o - DI)) * LL + l] = silu_f(acc);
}

// depthwise 3x3 SAME conv + bias + silu
__global__ void conv_k(const float* __restrict__ xx, const float* __restrict__ cw,
                       const float* __restrict__ cb, float* __restrict__ xc) {
    int idx = blockIdx.x * 256 + threadIdx.x;       // [b][d][hw]
    int hw = idx & (LL - 1);
    int d = (idx >> 10) % DI;
    int h = hw >> 5, w = hw & 31;
    int b = idx / (LL * DI);
    const float* xp = xx + ((size_t)b * DI + d) * LL;
    const float* wp = cw + d * 9;
    float acc = cb[d];
#pragma unroll
    for (int kh = 0; kh < 3; kh++) {
        int hh = h + kh - 1;
        if (hh < 0 || hh >= HH) continue;
#pragma unroll
        for (int kw = 0; kw < 3; kw++) {
            int ww2 = w + kw - 1;
            if (ww2 < 0 || ww2 >= WW) continue;
            acc = fmaf(xp[hh * WW + ww2], wp[kh * 3 + kw], acc);
        }
    }
    xc[idx] = silu_f(acc);
}

// xs_t[b][k][l][d] = xc[b][d][pos_k(l)]
__global__ void xs_k(const float* __restrict__ xc, float* __restrict__ xs) {
    int idx = blockIdx.x * 256 + threadIdx.x;
    int d = idx % DI;
    int rest = idx / DI;
    int l = rest & (LL - 1);
    int k = (rest >> 10) & 3;
    int b = rest >> 12;
    int pos = pos_k(k, l);
    xs[idx] = xc[((size_t)b * DI + d) * LL + pos];
}

// x_dbl[b][k][l][c(38)] = sum_d xs[b][k][l][d] * x_proj_w[k][c][d]
__global__ void xdbl_k(const float* __restrict__ xs, const float* __restrict__ xpw,
                       float* __restrict__ xdbl) {
    int idx = blockIdx.x * 256 + threadIdx.x;       // c fastest
    int c = idx % 38;
    int rest = idx / 38;
    int l = rest & (LL - 1);
    int bk = rest >> 10;
    int k = bk & 3;
    const float* xsv = xs + ((size_t)bk * LL + l) * DI;
    const float* wr = xpw + ((size_t)k * 38 + c) * DI;
    float acc = 0.f;
#pragma unroll 8
    for (int d = 0; d < DI; d++) acc = fmaf(xsv[d], wr[d], acc);
    xdbl[idx] = acc;
}

// ---- chunked parallel selective scan --------------------------------------
// phase 1: per-(bk,chunk) local scan from h=0; emit P = prod(a), Hloc = h_end
__global__ void scan_p1(const float* __restrict__ xs, const float* __restrict__ xdbl,
                        const float* __restrict__ dtw_g, const float* __restrict__ dtb_g,
                        const float* __restrict__ Alog,
                        float* __restrict__ Pst, float* __restrict__ Hloc) {
    int blk = blockIdx.x;           // bk*NC + c
    int bk = blk / NC, c = blk % NC;
    int k = bk & 3;
    int d = threadIdx.x;
    int kd = k * DI + d;

    float A[NS];
#pragma unroll
    for (int n = 0; n < NS; n++) A[n] = -__expf(Alog[(size_t)kd * NS + n]);
    float dtw[RK];
#pragma unroll
    for (int r = 0; r < RK; r++) dtw[r] = dtw_g[(size_t)kd * RK + r];
    float dtb = dtb_g[kd];

    float h[NS], P[NS];
#pragma unroll
    for (int n = 0; n < NS; n++) { h[n] = 0.f; P[n] = 1.f; }

    const float* xdbase = xdbl + ((size_t)bk * LL + c * CS) * 38;
    const float* xsbase = xs + ((size_t)bk * LL + c * CS) * DI;

    for (int s = 0; s < CS; s++) {
        const float* xd = xdbase + s * 38;
        float dt = dtb;
#pragma unroll
        for (int r = 0; r < RK; r++) dt = fmaf(xd[r], dtw[r], dt);
        dt = (dt > 20.f) ? dt : log1pf(__expf(dt));
        float du = dt * xsbase[(size_t)s * DI + d];
#pragma unroll
        for (int n = 0; n < NS; n++) {
            float a = __expf(dt * A[n]);
            h[n] = fmaf(a, h[n], du * xd[6 + n]);
            P[n] *= a;
        }
    }
    size_t base = ((size_t)blk * DI + d) * NS;
#pragma unroll
    for (int n = 0; n < NS; n++) { Pst[base + n] = P[n]; Hloc[base + n] = h[n]; }
}

// middle: sequential compose over chunks; Hloc becomes Hin (state entering chunk)
__global__ void scan_mid(const float* __restrict__ Pst, float* __restrict__ Hloc) {
    int bk = blockIdx.x;
    int d = threadIdx.x;
    float h[NS];
#pragma unroll
    for (int n = 0; n < NS; n++) h[n] = 0.f;
    for (int c = 0; c < NC; c++) {
        size_t base = (((size_t)bk * NC + c) * DI + d) * NS;
#pragma unroll
        for (int n = 0; n < NS; n++) {
            float p = Pst[base + n];
            float loc = Hloc[base + n];
            Hloc[base + n] = h[n];
            h[n] = fmaf(p, h[n], loc);
        }
    }
}

// phase 3: rerun each chunk seeded with Hin, emit y
__global__ void scan_p3(const float* __restrict__ xs, const float* __restrict__ xdbl,
                        const float* __restrict__ dtw_g, const float* __restrict__ dtb_g,
                        const float* __restrict__ Alog, const float* __restrict__ Ds,
                        const float* __restrict__ Hin, float* __restrict__ ys) {
    int blk = blockIdx.x;
    int bk = blk / NC, c = blk % NC;
    int k = bk & 3;
    int d = threadIdx.x;
    int kd = k * DI + d;

    float A[NS];
#pragma unroll
    for (int n = 0; n < NS; n++) A[n] = -__expf(Alog[(size_t)kd * NS + n]);
    float dtw[RK];
#pragma unroll
    for (int r = 0; r < RK; r++) dtw[r] = dtw_g[(size_t)kd * RK + r];
    float dtb = dtb_g[kd];
    float Dp = Ds[kd];

    float h[NS];
    size_t hbase = ((size_t)blk * DI + d) * NS;
#pragma unroll
    for (int n = 0; n < NS; n++) h[n] = Hin[hbase + n];

    const float* xdbase = xdbl + ((size_t)bk * LL + c * CS) * 38;
    const float* xsbase = xs + ((size_t)bk * LL + c * CS) * DI;
    float* ybase = ys + ((size_t)bk * LL + c * CS) * DI;

    for (int s = 0; s < CS; s++) {
        const float* xd = xdbase + s * 38;
        float dt = dtb;
#pragma unroll
        for (int r = 0; r < RK; r++) dt = fmaf(xd[r], dtw[r], dt);
        dt = (dt > 20.f) ? dt : log1pf(__expf(dt));
        float u = xsbase[(size_t)s * DI + d];
        float du = dt * u;
        float y = 0.f;
#pragma unroll
        for (int n = 0; n < NS; n++) {
            float a = __expf(dt * A[n]);
            h[n] = fmaf(a, h[n], du * xd[6 + n]);
            y = fmaf(h[n], xd[22 + n], y);
        }
        ybase[(size_t)s * DI + d] = fmaf(Dp, u, y);
    }
}
// ---------------------------------------------------------------------------

// cross_merge gather + per-batch sum/sumsq reduction
__global__ void merge_k(const float* __restrict__ ys, float* __restrict__ ym,
                        float* __restrict__ stats) {
    int b = blockIdx.y;
    int f = blockIdx.x * 256 + threadIdx.x;         // c*1024 + hw
    int c = f >> 10;
    int hw = f & 1023;
    int h = hw >> 5, w = hw & 31;

    int l0 = w * 32 + ((w & 1) ? 31 - h : h);
    int hh = 31 - h, ww = 31 - w;
    int l1 = ww * 32 + ((ww & 1) ? 31 - hh : hh);
    int l2 = h * 32 + ((h & 1) ? 31 - w : w);
    int l3 = hh * 32 + ((hh & 1) ? 31 - ww : ww);

    const float* yb = ys + (size_t)b * KK * LL * DI;
    float v = yb[((size_t)0 * LL + l0) * DI + c]
            + yb[((size_t)1 * LL + l1) * DI + c]
            + yb[((size_t)2 * LL + l2) * DI + c]
            + yb[((size_t)3 * LL + l3) * DI + c];
    ym[((size_t)b * DI + c) * LL + hw] = v;

    float s1 = v, s2 = v * v;
#pragma unroll
    for (int off = 32; off > 0; off >>= 1) {
        s1 += __shfl_down(s1, off);
        s2 += __shfl_down(s2, off);
    }
    __shared__ float sh1[4], sh2[4];
    int lane = threadIdx.x & 63, wid = threadIdx.x >> 6;
    if (lane == 0) { sh1[wid] = s1; sh2[wid] = s2; }
    __syncthreads();
    if (threadIdx.x == 0) {
        atomicAdd(&stats[b * 2],     sh1[0] + sh1[1] + sh1[2] + sh1[3]);
        atomicAdd(&stats[b * 2 + 1], sh2[0] + sh2[1] + sh2[2] + sh2[3]);
    }
}

// normalize + gamma/beta + multiply silu(z)
__global__ void yz_k(const float* __restrict__ ym, const float* __restrict__ zs,
                     const float* __restrict__ g, const float* __restrict__ be,
                     const float* __restrict__ stats, float* __restrict__ yz) {
    int idx = blockIdx.x * 256 + threadIdx.x;       // [b][c][hw]
    int c = (idx >> 10) % DI;
    int b = idx / (LL * DI);
    const float Ninv = 1.f / (float)(DI * LL);
    float mu = stats[b * 2] * Ninv;
    float var = stats[b * 2 + 1] * Ninv - mu * mu;
    float rstd = rsqrtf(var + 1e-6f);
    float v = (ym[idx] - mu) * rstd * g[c] + be[c];
    yz[idx] = v * zs[idx];
}

// out = einsum('bchw,oc->bohw')
__global__ void out_k(const float* __restrict__ yz, const float* __restrict__ wo,
                      float* __restrict__ out) {
    int idx = blockIdx.x * 256 + threadIdx.x;       // [b][o][hw]
    int hw = idx & 1023;
    int o = (idx >> 10) % DM;
    int b = idx / (LL * DM);
    const float* yb = yz + (size_t)b * DI * LL + hw;
    const float* wr = wo + o * DI;
    float acc = 0.f;
#pragma unroll 8
    for (int c = 0; c < DI; c++) acc = fmaf(yb[(size_t)c * LL], wr[c], acc);
    out[idx] = acc;
}

extern "C" void kernel_launch(void* const* d_in, const int* in_sizes, int n_in,
                              void* d_out, int out_size, void* d_ws, size_t ws_size,
                              hipStream_t stream) {
    const float* x    = (const float*)d_in[0];
    const float* ipw  = (const float*)d_in[1];
    const float* cw   = (const float*)d_in[2];
    const float* cb   = (const float*)d_in[3];
    const float* xpw  = (const float*)d_in[4];
    const float* dtw  = (const float*)d_in[5];
    const float* dtb  = (const float*)d_in[6];
    const float* Alog = (const float*)d_in[7];
    const float* Ds   = (const float*)d_in[8];
    const float* gng  = (const float*)d_in[9];
    const float* gnb  = (const float*)d_in[10];
    const float* opw  = (const float*)d_in[11];
    float* out = (float*)d_out;

    float* ws = (float*)d_ws;
    // arena (floats)
    const size_t o_xx   = 0;                                    // 786432 (reused as ym)
    const size_t o_zs   = o_xx + (size_t)Bsz * DI * LL;         // 786432
    const size_t o_xc   = o_zs + (size_t)Bsz * DI * LL;         // 786432 (reused as yz)
    const size_t o_xs   = o_xc + (size_t)Bsz * DI * LL;         // 3145728
    const size_t o_xdbl = o_xs + (size_t)Bsz * KK * LL * DI;    // 622592
    const size_t o_ys   = o_xdbl + (size_t)Bsz * KK * LL * 38;  // 3145728
    const size_t o_st   = o_ys + (size_t)Bsz * KK * LL * DI;    // 16 (pad)
    const size_t o_P    = o_st + 16;                            // 1572864
    const size_t o_H    = o_P + (size_t)Bsz * KK * NC * DI * NS;// 1572864
    // total ~12.4M floats = ~50 MB

    float* xx    = ws + o_xx;
    float* zs    = ws + o_zs;
    float* xc    = ws + o_xc;
    float* xs    = ws + o_xs;
    float* xdbl  = ws + o_xdbl;
    float* ys    = ws + o_ys;
    float* stats = ws + o_st;
    float* Pst   = ws + o_P;
    float* Hst   = ws + o_H;
    float* ym = xx;   // xx dead after conv
    float* yz = xc;   // xc dead after xs gather

    hipLaunchKernelGGL(zero_stats_k, dim3(1), dim3(64), 0, stream, stats);
    hipLaunchKernelGGL(in_proj_k, dim3(6144), dim3(256), 0, stream, x, ipw, xx, zs);
    hipLaunchKernelGGL(conv_k, dim3(3072), dim3(256), 0, stream, xx, cw, cb, xc);
    hipLaunchKernelGGL(xs_k, dim3(12288), dim3(256), 0, stream, xc, xs);
    hipLaunchKernelGGL(xdbl_k, dim3(2432), dim3(256), 0, stream, xs, xpw, xdbl);
    hipLaunchKernelGGL(scan_p1, dim3(Bsz * KK * NC), dim3(192), 0, stream,
                       xs, xdbl, dtw, dtb, Alog, Pst, Hst);
    hipLaunchKernelGGL(scan_mid, dim3(Bsz * KK), dim3(192), 0, stream, Pst, Hst);
    hipLaunchKernelGGL(scan_p3, dim3(Bsz * KK * NC), dim3(192), 0, stream,
                       xs, xdbl, dtw, dtb, Alog, Ds, Hst, ys);
    hipLaunchKernelGGL(merge_k, dim3(768, 4), dim3(256), 0, stream, ys, ym, stats);
    hipLaunchKernelGGL(yz_k, dim3(3072), dim3(256), 0, stream, ym, zs, gng, gnb, stats, yz);
    hipLaunchKernelGGL(out_k, dim3(1536), dim3(256), 0, stream, yz, opw, out);
}

// Round 3
// 332.216 us; speedup vs baseline: 3.5116x; 1.2714x over previous
//
#include <hip/hip_runtime.h>
#include <math.h>

#define Bsz 4
#define DM 96
#define DI 192
#define NS 16
#define RK 6
#define KK 4
#define HH 32
#define WW 32
#define LL 1024
#define NC 64          // chunks along L
#define CS 16          // chunk size (NC*CS == LL)

__device__ __forceinline__ float silu_f(float x) { return x / (1.f + __expf(-x)); }

// inverse snake maps: (h,w) -> scan position l for direction k (verified in r1/r2)
__device__ __forceinline__ int l_of_hw(int k, int h, int w) {
    if (k == 1 || k == 3) { h = 31 - h; w = 31 - w; }
    if (k < 2) return w * 32 + ((w & 1) ? 31 - h : h);      // vertical snake
    return h * 32 + ((h & 1) ? 31 - w : w);                 // horizontal snake
}

// ---- in_proj: 8 outputs per thread; also zeroes stats ---------------------
__global__ void in_proj_k(const float* __restrict__ x, const float* __restrict__ w,
                          float* __restrict__ xx, float* __restrict__ zs,
                          float* __restrict__ stats) {
    int bi = blockIdx.x;                 // 4 lblk * 48 og * 4 b
    int t = threadIdx.x;
    if (bi == 0 && t < 2 * Bsz) stats[t] = 0.f;
    int lb = bi & 3;
    int og = (bi >> 2) % 48;
    int b = bi / 192;
    int l = lb * 256 + t;
    const float* xb = x + (size_t)b * DM * LL + l;
    float acc[8];
#pragma unroll
    for (int g = 0; g < 8; g++) acc[g] = 0.f;
    for (int c = 0; c < DM; c++) {
        float xv = xb[(size_t)c * LL];
#pragma unroll
        for (int g = 0; g < 8; g++)
            acc[g] = fmaf(xv, w[(size_t)(og * 8 + g) * DM + c], acc[g]);
    }
#pragma unroll
    for (int g = 0; g < 8; g++) {
        int o = og * 8 + g;
        if (o < DI) xx[((size_t)b * DI + o) * LL + l] = acc[g];
        else        zs[((size_t)b * DI + (o - DI)) * LL + l] = silu_f(acc[g]);
    }
}

// ---- fused depthwise conv3x3+silu + cross-scan gather ---------------------
// block: one image row (h0), 64-channel tile (d0), one batch
// writes xs[b][k][l][d] for all 4 directions, d-contiguous (coalesced)
__global__ void convxs_k(const float* __restrict__ xx, const float* __restrict__ cw,
                         const float* __restrict__ cb, float* __restrict__ xs) {
    __shared__ float tile[32][65];       // [wi][di], pad for conflict-free transpose
    int bi = blockIdx.x;                 // 32 rows * 3 dtiles * 4 b
    int h0 = bi % 32;
    int dt = (bi / 32) % 3;
    int b = bi / 96;
    int d0 = dt * 64;
    int t = threadIdx.x;
    int wi = t & 31, dg = t >> 5;        // dg in 0..7

#pragma unroll
    for (int pass = 0; pass < 8; pass++) {
        int di = pass * 8 + dg;
        int d = d0 + di;
        const float* xp = xx + ((size_t)b * DI + d) * LL;
        const float* wp = cw + d * 9;
        float acc = cb[d];
#pragma unroll
        for (int kh = 0; kh < 3; kh++) {
            int hh = h0 + kh - 1;
            if (hh < 0 || hh >= HH) continue;
#pragma unroll
            for (int kw = 0; kw < 3; kw++) {
                int ww2 = wi + kw - 1;
                if (ww2 < 0 || ww2 >= WW) continue;
                acc = fmaf(xp[hh * WW + ww2], wp[kh * 3 + kw], acc);
            }
        }
        tile[wi][di] = silu_f(acc);
    }
    __syncthreads();

    // write 4 direction copies: t -> di fastest (contiguous 64-float rows)
    int di = t & 63, hg = t >> 6;        // hg in 0..3
#pragma unroll
    for (int k = 0; k < KK; k++) {
        float* xsk = xs + ((size_t)b * KK + k) * LL * DI;
#pragma unroll
        for (int rep = 0; rep < 8; rep++) {
            int w2 = rep * 4 + hg;
            int l = l_of_hw(k, h0, w2);
            xsk[(size_t)l * DI + d0 + di] = tile[w2][di];
        }
    }
}

// x_dbl[b][k][l][c(38)] = sum_d xs[b][k][l][d] * x_proj_w[k][c][d]
__global__ void xdbl_k(const float* __restrict__ xs, const float* __restrict__ xpw,
                       float* __restrict__ xdbl) {
    int idx = blockIdx.x * 256 + threadIdx.x;       // c fastest
    int c = idx % 38;
    int rest = idx / 38;
    int l = rest & (LL - 1);
    int bk = rest >> 10;
    int k = bk & 3;
    const float* xsv = xs + ((size_t)bk * LL + l) * DI;
    const float* wr = xpw + ((size_t)k * 38 + c) * DI;
    float acc = 0.f;
#pragma unroll 8
    for (int d = 0; d < DI; d++) acc = fmaf(xsv[d], wr[d], acc);
    xdbl[idx] = acc;
}

// ---- chunked parallel selective scan --------------------------------------
__global__ void scan_p1(const float* __restrict__ xs, const float* __restrict__ xdbl,
                        const float* __restrict__ dtw_g, const float* __restrict__ dtb_g,
                        const float* __restrict__ Alog,
                        float* __restrict__ Pst, float* __restrict__ Hloc) {
    int blk = blockIdx.x;           // bk*NC + c
    int bk = blk / NC, c = blk % NC;
    int k = bk & 3;
    int d = threadIdx.x;
    int kd = k * DI + d;

    float A[NS];
#pragma unroll
    for (int n = 0; n < NS; n++) A[n] = -__expf(Alog[(size_t)kd * NS + n]);
    float dtw[RK];
#pragma unroll
    for (int r = 0; r < RK; r++) dtw[r] = dtw_g[(size_t)kd * RK + r];
    float dtb = dtb_g[kd];

    float h[NS], P[NS];
#pragma unroll
    for (int n = 0; n < NS; n++) { h[n] = 0.f; P[n] = 1.f; }

    const float* xdbase = xdbl + ((size_t)bk * LL + c * CS) * 38;
    const float* xsbase = xs + ((size_t)bk * LL + c * CS) * DI;

    for (int s = 0; s < CS; s++) {
        const float* xd = xdbase + s * 38;
        float dt = dtb;
#pragma unroll
        for (int r = 0; r < RK; r++) dt = fmaf(xd[r], dtw[r], dt);
        dt = (dt > 20.f) ? dt : log1pf(__expf(dt));
        float du = dt * xsbase[(size_t)s * DI + d];
#pragma unroll
        for (int n = 0; n < NS; n++) {
            float a = __expf(dt * A[n]);
            h[n] = fmaf(a, h[n], du * xd[6 + n]);
            P[n] *= a;
        }
    }
    size_t base = ((size_t)blk * DI + d) * NS;
#pragma unroll
    for (int n = 0; n < NS; n++) { Pst[base + n] = P[n]; Hloc[base + n] = h[n]; }
}

__global__ void scan_mid(const float* __restrict__ Pst, float* __restrict__ Hloc) {
    int bk = blockIdx.x;
    int d = threadIdx.x;
    float h[NS];
#pragma unroll
    for (int n = 0; n < NS; n++) h[n] = 0.f;
    for (int c = 0; c < NC; c++) {
        size_t base = (((size_t)bk * NC + c) * DI + d) * NS;
#pragma unroll
        for (int n = 0; n < NS; n++) {
            float p = Pst[base + n];
            float loc = Hloc[base + n];
            Hloc[base + n] = h[n];
            h[n] = fmaf(p, h[n], loc);
        }
    }
}

__global__ void scan_p3(const float* __restrict__ xs, const float* __restrict__ xdbl,
                        const float* __restrict__ dtw_g, const float* __restrict__ dtb_g,
                        const float* __restrict__ Alog, const float* __restrict__ Ds,
                        const float* __restrict__ Hin, float* __restrict__ ys) {
    int blk = blockIdx.x;
    int bk = blk / NC, c = blk % NC;
    int k = bk & 3;
    int d = threadIdx.x;
    int kd = k * DI + d;

    float A[NS];
#pragma unroll
    for (int n = 0; n < NS; n++) A[n] = -__expf(Alog[(size_t)kd * NS + n]);
    float dtw[RK];
#pragma unroll
    for (int r = 0; r < RK; r++) dtw[r] = dtw_g[(size_t)kd * RK + r];
    float dtb = dtb_g[kd];
    float Dp = Ds[kd];

    float h[NS];
    size_t hbase = ((size_t)blk * DI + d) * NS;
#pragma unroll
    for (int n = 0; n < NS; n++) h[n] = Hin[hbase + n];

    const float* xdbase = xdbl + ((size_t)bk * LL + c * CS) * 38;
    const float* xsbase = xs + ((size_t)bk * LL + c * CS) * DI;
    float* ybase = ys + ((size_t)bk * LL + c * CS) * DI;

    for (int s = 0; s < CS; s++) {
        const float* xd = xdbase + s * 38;
        float dt = dtb;
#pragma unroll
        for (int r = 0; r < RK; r++) dt = fmaf(xd[r], dtw[r], dt);
        dt = (dt > 20.f) ? dt : log1pf(__expf(dt));
        float u = xsbase[(size_t)s * DI + d];
        float du = dt * u;
        float y = 0.f;
#pragma unroll
        for (int n = 0; n < NS; n++) {
            float a = __expf(dt * A[n]);
            h[n] = fmaf(a, h[n], du * xd[6 + n]);
            y = fmaf(h[n], xd[22 + n], y);
        }
        ybase[(size_t)s * DI + d] = fmaf(Dp, u, y);
    }
}

// ---- cross-merge: coalesced reads (thread=d), LDS transpose, stats --------
#define MT 16
__global__ void merge_k(const float* __restrict__ ys, float* __restrict__ ym,
                        float* __restrict__ stats) {
    __shared__ float tile[MT][DI + 1];
    __shared__ float sh1[3], sh2[3];
    int b = blockIdx.y;
    int hw0 = blockIdx.x * MT;
    int d = threadIdx.x;
    const float* yb = ys + (size_t)b * KK * LL * DI;

    float s1 = 0.f, s2 = 0.f;
#pragma unroll
    for (int hwi = 0; hwi < MT; hwi++) {
        int hw = hw0 + hwi;
        int h = hw >> 5, w = hw & 31;
        int l0 = l_of_hw(0, h, w);
        int l1 = l_of_hw(1, h, w);
        int l2 = l_of_hw(2, h, w);
        int l3 = l_of_hw(3, h, w);
        float v = yb[((size_t)0 * LL + l0) * DI + d]
                + yb[((size_t)1 * LL + l1) * DI + d]
                + yb[((size_t)2 * LL + l2) * DI + d]
                + yb[((size_t)3 * LL + l3) * DI + d];
        tile[hwi][d] = v;
        s1 += v; s2 = fmaf(v, v, s2);
    }
#pragma unroll
    for (int off = 32; off > 0; off >>= 1) {
        s1 += __shfl_down(s1, off);
        s2 += __shfl_down(s2, off);
    }
    int lane = threadIdx.x & 63, wid = threadIdx.x >> 6;
    if (lane == 0) { sh1[wid] = s1; sh2[wid] = s2; }
    __syncthreads();
    if (threadIdx.x == 0) {
        atomicAdd(&stats[b * 2],     sh1[0] + sh1[1] + sh1[2]);
        atomicAdd(&stats[b * 2 + 1], sh2[0] + sh2[1] + sh2[2]);
    }
    // coalesced write-out: consecutive threads -> consecutive hw
#pragma unroll
    for (int rep = 0; rep < MT; rep++) {
        int j = rep * DI + threadIdx.x;
        int d2 = j >> 4;          // j / MT
        int hwi = j & (MT - 1);
        ym[((size_t)b * DI + d2) * LL + hw0 + hwi] = tile[hwi][d2];
    }
}

// normalize + gamma/beta + multiply silu(z)
__global__ void yz_k(const float* __restrict__ ym, const float* __restrict__ zs,
                     const float* __restrict__ g, const float* __restrict__ be,
                     const float* __restrict__ stats, float* __restrict__ yz) {
    int idx = blockIdx.x * 256 + threadIdx.x;       // [b][c][hw]
    int c = (idx >> 10) % DI;
    int b = idx / (LL * DI);
    const float Ninv = 1.f / (float)(DI * LL);
    float mu = stats[b * 2] * Ninv;
    float var = stats[b * 2 + 1] * Ninv - mu * mu;
    float rstd = rsqrtf(var + 1e-6f);
    float v = (ym[idx] - mu) * rstd * g[c] + be[c];
    yz[idx] = v * zs[idx];
}

// out projection: 4 outputs per thread
__global__ void out_k(const float* __restrict__ yz, const float* __restrict__ wo,
                      float* __restrict__ out) {
    int bi = blockIdx.x;                 // 4 lblk * 24 og * 4 b
    int t = threadIdx.x;
    int lb = bi & 3;
    int og = (bi >> 2) % 24;
    int b = bi / 96;
    int l = lb * 256 + t;
    const float* yb = yz + (size_t)b * DI * LL + l;
    float acc[4];
#pragma unroll
    for (int g = 0; g < 4; g++) acc[g] = 0.f;
    for (int c = 0; c < DI; c++) {
        float yv = yb[(size_t)c * LL];
#pragma unroll
        for (int g = 0; g < 4; g++)
            acc[g] = fmaf(yv, wo[(size_t)(og * 4 + g) * DI + c], acc[g]);
    }
#pragma unroll
    for (int g = 0; g < 4; g++)
        out[((size_t)b * DM + og * 4 + g) * LL + l] = acc[g];
}

extern "C" void kernel_launch(void* const* d_in, const int* in_sizes, int n_in,
                              void* d_out, int out_size, void* d_ws, size_t ws_size,
                              hipStream_t stream) {
    const float* x    = (const float*)d_in[0];
    const float* ipw  = (const float*)d_in[1];
    const float* cw   = (const float*)d_in[2];
    const float* cb   = (const float*)d_in[3];
    const float* xpw  = (const float*)d_in[4];
    const float* dtw  = (const float*)d_in[5];
    const float* dtb  = (const float*)d_in[6];
    const float* Alog = (const float*)d_in[7];
    const float* Ds   = (const float*)d_in[8];
    const float* gng  = (const float*)d_in[9];
    const float* gnb  = (const float*)d_in[10];
    const float* opw  = (const float*)d_in[11];
    float* out = (float*)d_out;

    float* ws = (float*)d_ws;
    // arena (floats), ~46.5 MB total
    const size_t o_xx   = 0;                                     // 786432 (→ ym)
    const size_t o_zs   = o_xx + (size_t)Bsz * DI * LL;          // 786432
    const size_t o_xs   = o_zs + (size_t)Bsz * DI * LL;          // 3145728
    const size_t o_xdbl = o_xs + (size_t)Bsz * KK * LL * DI;     // 622592
    const size_t o_P    = o_xdbl + (size_t)Bsz * KK * LL * 38;   // 3145728 (→ ys)
    const size_t o_H    = o_P + (size_t)Bsz * KK * NC * DI * NS; // 3145728 (→ yz)
    const size_t o_st   = o_H + (size_t)Bsz * KK * NC * DI * NS; // 16

    float* xx    = ws + o_xx;
    float* zs    = ws + o_zs;
    float* xs    = ws + o_xs;
    float* xdbl  = ws + o_xdbl;
    float* Pst   = ws + o_P;
    float* Hst   = ws + o_H;
    float* stats = ws + o_st;
    float* ys = Pst;   // Pst dead after scan_mid
    float* ym = xx;    // xx dead after convxs
    float* yz = Hst;   // Hst dead after scan_p3

    hipLaunchKernelGGL(in_proj_k, dim3(768), dim3(256), 0, stream, x, ipw, xx, zs, stats);
    hipLaunchKernelGGL(convxs_k, dim3(384), dim3(256), 0, stream, xx, cw, cb, xs);
    hipLaunchKernelGGL(xdbl_k, dim3(2432), dim3(256), 0, stream, xs, xpw, xdbl);
    hipLaunchKernelGGL(scan_p1, dim3(Bsz * KK * NC), dim3(192), 0, stream,
                       xs, xdbl, dtw, dtb, Alog, Pst, Hst);
    hipLaunchKernelGGL(scan_mid, dim3(Bsz * KK), dim3(192), 0, stream, Pst, Hst);
    hipLaunchKernelGGL(scan_p3, dim3(Bsz * KK * NC), dim3(192), 0, stream,
                       xs, xdbl, dtw, dtb, Alog, Ds, Hst, ys);
    hipLaunchKernelGGL(merge_k, dim3(LL / MT, Bsz), dim3(192), 0, stream, ys, ym, stats);
    hipLaunchKernelGGL(yz_k, dim3(3072), dim3(256), 0, stream, ym, zs, gng, gnb, stats, yz);
    hipLaunchKernelGGL(out_k, dim3(384), dim3(256), 0, stream, yz, opw, out);
}

// Round 4
// 233.737 us; speedup vs baseline: 4.9912x; 1.4213x over previous
//
#include <hip/hip_runtime.h>
#include <math.h>

#define Bsz 4
#define DM 96
#define DI 192
#define NS 16
#define RK 6
#define KK 4
#define HH 32
#define WW 32
#define LL 1024
#define NC 64          // chunks along L
#define CS 16          // chunk size (NC*CS == LL)

__device__ __forceinline__ float silu_f(float x) { return x / (1.f + __expf(-x)); }

// inverse snake maps: (h,w) -> scan position l for direction k (verified r1/r2)
__device__ __forceinline__ int l_of_hw(int k, int h, int w) {
    if (k == 1 || k == 3) { h = 31 - h; w = 31 - w; }
    if (k < 2) return w * 32 + ((w & 1) ? 31 - h : h);      // vertical snake
    return h * 32 + ((h & 1) ? 31 - w : w);                 // horizontal snake
}

// ---- in_proj: 8 outputs per thread; also zeroes stats ---------------------
__global__ void in_proj_k(const float* __restrict__ x, const float* __restrict__ w,
                          float* __restrict__ xx, float* __restrict__ zs,
                          float* __restrict__ stats) {
    int bi = blockIdx.x;                 // 4 lblk * 48 og * 4 b
    int t = threadIdx.x;
    if (bi == 0 && t < 2 * Bsz) stats[t] = 0.f;
    int lb = bi & 3;
    int og = (bi >> 2) % 48;
    int b = bi / 192;
    int l = lb * 256 + t;
    const float* xb = x + (size_t)b * DM * LL + l;
    float acc[8];
#pragma unroll
    for (int g = 0; g < 8; g++) acc[g] = 0.f;
    for (int c = 0; c < DM; c++) {
        float xv = xb[(size_t)c * LL];
#pragma unroll
        for (int g = 0; g < 8; g++)
            acc[g] = fmaf(xv, w[(size_t)(og * 8 + g) * DM + c], acc[g]);
    }
#pragma unroll
    for (int g = 0; g < 8; g++) {
        int o = og * 8 + g;
        if (o < DI) xx[((size_t)b * DI + o) * LL + l] = acc[g];
        else        zs[((size_t)b * DI + (o - DI)) * LL + l] = silu_f(acc[g]);
    }
}

// ---- fused depthwise conv3x3+silu + cross-scan gather ---------------------
__global__ void convxs_k(const float* __restrict__ xx, const float* __restrict__ cw,
                         const float* __restrict__ cb, float* __restrict__ xs) {
    __shared__ float tile[32][65];
    int bi = blockIdx.x;                 // 32 rows * 3 dtiles * 4 b
    int h0 = bi % 32;
    int dt = (bi / 32) % 3;
    int b = bi / 96;
    int d0 = dt * 64;
    int t = threadIdx.x;
    int wi = t & 31, dg = t >> 5;

#pragma unroll
    for (int pass = 0; pass < 8; pass++) {
        int di = pass * 8 + dg;
        int d = d0 + di;
        const float* xp = xx + ((size_t)b * DI + d) * LL;
        const float* wp = cw + d * 9;
        float acc = cb[d];
#pragma unroll
        for (int kh = 0; kh < 3; kh++) {
            int hh = h0 + kh - 1;
            if (hh < 0 || hh >= HH) continue;
#pragma unroll
            for (int kw = 0; kw < 3; kw++) {
                int ww2 = wi + kw - 1;
                if (ww2 < 0 || ww2 >= WW) continue;
                acc = fmaf(xp[hh * WW + ww2], wp[kh * 3 + kw], acc);
            }
        }
        tile[wi][di] = silu_f(acc);
    }
    __syncthreads();

    int di = t & 63, hg = t >> 6;
#pragma unroll
    for (int k = 0; k < KK; k++) {
        float* xsk = xs + ((size_t)b * KK + k) * LL * DI;
#pragma unroll
        for (int rep = 0; rep < 8; rep++) {
            int w2 = rep * 4 + hg;
            int l = l_of_hw(k, h0, w2);
            xsk[(size_t)l * DI + d0 + di] = tile[w2][di];
        }
    }
}

// ---- x_dbl: tiled GEMM. block = (bk, ltile of 64); 512 threads ------------
// LDS-staged xs tile (coalesced float4), wave-uniform c-group -> scalar
// weight loads, 5 accumulators/thread.
__global__ void __launch_bounds__(512)
xdbl_k(const float* __restrict__ xs, const float* __restrict__ xpw,
       float* __restrict__ xdbl) {
    __shared__ float tile[64 * 193];
    int blk = blockIdx.x;            // bk*16 + lt
    int bk = blk >> 4, lt = blk & 15;
    int k = bk & 3;
    int t = threadIdx.x;

    // stage 64 x 192 floats = 3072 float4, fully coalesced
    const float4* src4 = (const float4*)(xs + ((size_t)bk * LL + lt * 64) * DI);
#pragma unroll
    for (int i = 0; i < 6; i++) {
        int j4 = t + i * 512;
        float4 v = src4[j4];
        int l = j4 / 48;            // 48 float4 per row
        int d = (j4 % 48) * 4;
        float* dst = &tile[l * 193 + d];
        dst[0] = v.x; dst[1] = v.y; dst[2] = v.z; dst[3] = v.w;
    }
    __syncthreads();

    int ll = t & 63;                 // lane -> l (distinct per lane, 2-way bank = free)
    int cg = t >> 6;                 // wave-uniform c-group 0..7
    int c0 = cg * 5;
    int wlim = (c0 + 5 <= 38) ? 5 : (38 - c0);   // 5,...,5,3
    const float* wk = xpw + (size_t)k * 38 * DI;

    float acc[5];
#pragma unroll
    for (int j = 0; j < 5; j++) acc[j] = 0.f;
    const float* xrow = &tile[ll * 193];
#pragma unroll 4
    for (int d = 0; d < DI; d++) {
        float xv = xrow[d];
#pragma unroll
        for (int j = 0; j < 5; j++) {
            int cc = c0 + j; cc = (cc > 37) ? 37 : cc;    // clamp, discard at write
            acc[j] = fmaf(xv, wk[(size_t)cc * DI + d], acc[j]);
        }
    }
    float* orow = xdbl + ((size_t)bk * LL + lt * 64 + ll) * 38;
#pragma unroll
    for (int j = 0; j < 5; j++)
        if (j < wlim) orow[c0 + j] = acc[j];
}

// ---- chunked parallel selective scan --------------------------------------
__global__ void scan_p1(const float* __restrict__ xs, const float* __restrict__ xdbl,
                        const float* __restrict__ dtw_g, const float* __restrict__ dtb_g,
                        const float* __restrict__ Alog,
                        float* __restrict__ Pst, float* __restrict__ Hloc) {
    int blk = blockIdx.x;           // bk*NC + c
    int bk = blk / NC, c = blk % NC;
    int k = bk & 3;
    int d = threadIdx.x;
    int kd = k * DI + d;

    float A[NS];
#pragma unroll
    for (int n = 0; n < NS; n++) A[n] = -__expf(Alog[(size_t)kd * NS + n]);
    float dtw[RK];
#pragma unroll
    for (int r = 0; r < RK; r++) dtw[r] = dtw_g[(size_t)kd * RK + r];
    float dtb = dtb_g[kd];

    float h[NS], P[NS];
#pragma unroll
    for (int n = 0; n < NS; n++) { h[n] = 0.f; P[n] = 1.f; }

    const float* xdbase = xdbl + ((size_t)bk * LL + c * CS) * 38;
    const float* xsbase = xs + ((size_t)bk * LL + c * CS) * DI;

    for (int s = 0; s < CS; s++) {
        const float* xd = xdbase + s * 38;
        float dt = dtb;
#pragma unroll
        for (int r = 0; r < RK; r++) dt = fmaf(xd[r], dtw[r], dt);
        dt = (dt > 20.f) ? dt : log1pf(__expf(dt));
        float du = dt * xsbase[(size_t)s * DI + d];
#pragma unroll
        for (int n = 0; n < NS; n++) {
            float a = __expf(dt * A[n]);
            h[n] = fmaf(a, h[n], du * xd[6 + n]);
            P[n] *= a;
        }
    }
    size_t base = ((size_t)blk * DI + d) * NS;
#pragma unroll
    for (int n = 0; n < NS; n++) { Pst[base + n] = P[n]; Hloc[base + n] = h[n]; }
}

// middle compose: one thread per (bk,d,n); loads pipeline ahead of fma chain
__global__ void scan_mid(const float* __restrict__ Pst, float* __restrict__ Hloc) {
    int gid = blockIdx.x * 256 + threadIdx.x;     // bk*(DI*NS) + d*NS + n
    int bk = gid / (DI * NS);
    int dn = gid % (DI * NS);
    size_t base = (size_t)bk * NC * DI * NS + dn;
    float h = 0.f;
    for (int c = 0; c < NC; c++) {
        size_t a = base + (size_t)c * DI * NS;
        float p = Pst[a];
        float loc = Hloc[a];
        Hloc[a] = h;
        h = fmaf(p, h, loc);
    }
}

__global__ void scan_p3(const float* __restrict__ xs, const float* __restrict__ xdbl,
                        const float* __restrict__ dtw_g, const float* __restrict__ dtb_g,
                        const float* __restrict__ Alog, const float* __restrict__ Ds,
                        const float* __restrict__ Hin, float* __restrict__ ys) {
    int blk = blockIdx.x;
    int bk = blk / NC, c = blk % NC;
    int k = bk & 3;
    int d = threadIdx.x;
    int kd = k * DI + d;

    float A[NS];
#pragma unroll
    for (int n = 0; n < NS; n++) A[n] = -__expf(Alog[(size_t)kd * NS + n]);
    float dtw[RK];
#pragma unroll
    for (int r = 0; r < RK; r++) dtw[r] = dtw_g[(size_t)kd * RK + r];
    float dtb = dtb_g[kd];
    float Dp = Ds[kd];

    float h[NS];
    size_t hbase = ((size_t)blk * DI + d) * NS;
#pragma unroll
    for (int n = 0; n < NS; n++) h[n] = Hin[hbase + n];

    const float* xdbase = xdbl + ((size_t)bk * LL + c * CS) * 38;
    const float* xsbase = xs + ((size_t)bk * LL + c * CS) * DI;
    float* ybase = ys + ((size_t)bk * LL + c * CS) * DI;

    for (int s = 0; s < CS; s++) {
        const float* xd = xdbase + s * 38;
        float dt = dtb;
#pragma unroll
        for (int r = 0; r < RK; r++) dt = fmaf(xd[r], dtw[r], dt);
        dt = (dt > 20.f) ? dt : log1pf(__expf(dt));
        float u = xsbase[(size_t)s * DI + d];
        float du = dt * u;
        float y = 0.f;
#pragma unroll
        for (int n = 0; n < NS; n++) {
            float a = __expf(dt * A[n]);
            h[n] = fmaf(a, h[n], du * xd[6 + n]);
            y = fmaf(h[n], xd[22 + n], y);
        }
        ybase[(size_t)s * DI + d] = fmaf(Dp, u, y);
    }
}

// ---- cross-merge: coalesced reads (thread=d), LDS transpose, stats --------
#define MT 16
__global__ void merge_k(const float* __restrict__ ys, float* __restrict__ ym,
                        float* __restrict__ stats) {
    __shared__ float tile[MT][DI + 1];
    __shared__ float sh1[3], sh2[3];
    int b = blockIdx.y;
    int hw0 = blockIdx.x * MT;
    int d = threadIdx.x;
    const float* yb = ys + (size_t)b * KK * LL * DI;

    float s1 = 0.f, s2 = 0.f;
#pragma unroll
    for (int hwi = 0; hwi < MT; hwi++) {
        int hw = hw0 + hwi;
        int h = hw >> 5, w = hw & 31;
        int l0 = l_of_hw(0, h, w);
        int l1 = l_of_hw(1, h, w);
        int l2 = l_of_hw(2, h, w);
        int l3 = l_of_hw(3, h, w);
        float v = yb[((size_t)0 * LL + l0) * DI + d]
                + yb[((size_t)1 * LL + l1) * DI + d]
                + yb[((size_t)2 * LL + l2) * DI + d]
                + yb[((size_t)3 * LL + l3) * DI + d];
        tile[hwi][d] = v;
        s1 += v; s2 = fmaf(v, v, s2);
    }
#pragma unroll
    for (int off = 32; off > 0; off >>= 1) {
        s1 += __shfl_down(s1, off);
        s2 += __shfl_down(s2, off);
    }
    int lane = threadIdx.x & 63, wid = threadIdx.x >> 6;
    if (lane == 0) { sh1[wid] = s1; sh2[wid] = s2; }
    __syncthreads();
    if (threadIdx.x == 0) {
        atomicAdd(&stats[b * 2],     sh1[0] + sh1[1] + sh1[2]);
        atomicAdd(&stats[b * 2 + 1], sh2[0] + sh2[1] + sh2[2]);
    }
#pragma unroll
    for (int rep = 0; rep < MT; rep++) {
        int j = rep * DI + threadIdx.x;
        int d2 = j >> 4;
        int hwi = j & (MT - 1);
        ym[((size_t)b * DI + d2) * LL + hw0 + hwi] = tile[hwi][d2];
    }
}

// normalize + gamma/beta + multiply silu(z)
__global__ void yz_k(const float* __restrict__ ym, const float* __restrict__ zs,
                     const float* __restrict__ g, const float* __restrict__ be,
                     const float* __restrict__ stats, float* __restrict__ yz) {
    int idx = blockIdx.x * 256 + threadIdx.x;
    int c = (idx >> 10) % DI;
    int b = idx / (LL * DI);
    const float Ninv = 1.f / (float)(DI * LL);
    float mu = stats[b * 2] * Ninv;
    float var = stats[b * 2 + 1] * Ninv - mu * mu;
    float rstd = rsqrtf(var + 1e-6f);
    float v = (ym[idx] - mu) * rstd * g[c] + be[c];
    yz[idx] = v * zs[idx];
}

// out projection: 4 outputs per thread
__global__ void out_k(const float* __restrict__ yz, const float* __restrict__ wo,
                      float* __restrict__ out) {
    int bi = blockIdx.x;                 // 4 lblk * 24 og * 4 b
    int t = threadIdx.x;
    int lb = bi & 3;
    int og = (bi >> 2) % 24;
    int b = bi / 96;
    int l = lb * 256 + t;
    const float* yb = yz + (size_t)b * DI * LL + l;
    float acc[4];
#pragma unroll
    for (int g = 0; g < 4; g++) acc[g] = 0.f;
    for (int c = 0; c < DI; c++) {
        float yv = yb[(size_t)c * LL];
#pragma unroll
        for (int g = 0; g < 4; g++)
            acc[g] = fmaf(yv, wo[(size_t)(og * 4 + g) * DI + c], acc[g]);
    }
#pragma unroll
    for (int g = 0; g < 4; g++)
        out[((size_t)b * DM + og * 4 + g) * LL + l] = acc[g];
}

extern "C" void kernel_launch(void* const* d_in, const int* in_sizes, int n_in,
                              void* d_out, int out_size, void* d_ws, size_t ws_size,
                              hipStream_t stream) {
    const float* x    = (const float*)d_in[0];
    const float* ipw  = (const float*)d_in[1];
    const float* cw   = (const float*)d_in[2];
    const float* cb   = (const float*)d_in[3];
    const float* xpw  = (const float*)d_in[4];
    const float* dtw  = (const float*)d_in[5];
    const float* dtb  = (const float*)d_in[6];
    const float* Alog = (const float*)d_in[7];
    const float* Ds   = (const float*)d_in[8];
    const float* gng  = (const float*)d_in[9];
    const float* gnb  = (const float*)d_in[10];
    const float* opw  = (const float*)d_in[11];
    float* out = (float*)d_out;

    float* ws = (float*)d_ws;
    const size_t o_xx   = 0;                                     // (→ ym)
    const size_t o_zs   = o_xx + (size_t)Bsz * DI * LL;
    const size_t o_xs   = o_zs + (size_t)Bsz * DI * LL;
    const size_t o_xdbl = o_xs + (size_t)Bsz * KK * LL * DI;
    const size_t o_P    = o_xdbl + (size_t)Bsz * KK * LL * 38;   // (→ ys)
    const size_t o_H    = o_P + (size_t)Bsz * KK * NC * DI * NS; // (→ yz)
    const size_t o_st   = o_H + (size_t)Bsz * KK * NC * DI * NS;

    float* xx    = ws + o_xx;
    float* zs    = ws + o_zs;
    float* xs    = ws + o_xs;
    float* xdbl  = ws + o_xdbl;
    float* Pst   = ws + o_P;
    float* Hst   = ws + o_H;
    float* stats = ws + o_st;
    float* ys = Pst;   // Pst dead after scan_mid
    float* ym = xx;    // xx dead after convxs
    float* yz = Hst;   // Hst dead after scan_p3

    hipLaunchKernelGGL(in_proj_k, dim3(768), dim3(256), 0, stream, x, ipw, xx, zs, stats);
    hipLaunchKernelGGL(convxs_k, dim3(384), dim3(256), 0, stream, xx, cw, cb, xs);
    hipLaunchKernelGGL(xdbl_k, dim3(256), dim3(512), 0, stream, xs, xpw, xdbl);
    hipLaunchKernelGGL(scan_p1, dim3(Bsz * KK * NC), dim3(192), 0, stream,
                       xs, xdbl, dtw, dtb, Alog, Pst, Hst);
    hipLaunchKernelGGL(scan_mid, dim3(192), dim3(256), 0, stream, Pst, Hst);
    hipLaunchKernelGGL(scan_p3, dim3(Bsz * KK * NC), dim3(192), 0, stream,
                       xs, xdbl, dtw, dtb, Alog, Ds, Hst, ys);
    hipLaunchKernelGGL(merge_k, dim3(LL / MT, Bsz), dim3(192), 0, stream, ys, ym, stats);
    hipLaunchKernelGGL(yz_k, dim3(3072), dim3(256), 0, stream, ym, zs, gng, gnb, stats, yz);
    hipLaunchKernelGGL(out_k, dim3(384), dim3(256), 0, stream, yz, opw, out);
}